// Round 2
// baseline (116637.231 us; speedup 1.0000x reference)
//
#include <hip/hip_runtime.h>

// Problem constants
#define NB   128        // batch
#define LSEQ 2048       // sequence length
#define HID  512        // hidden
#define EMB  256        // embed
#define KD   768        // HID + EMB
// Tiling: 256 workgroups = 2 n-groups x 128 h-blocks; 512 threads = 64n x 4h x 2kq
#define NT   64         // n-tile per workgroup
#define HT   4          // h-tile per workgroup
#define NGR  (NB/NT)    // 2 n-groups
#define HBL  (HID/HT)   // 128 h-blocks
#define NWG  (NGR*HBL)  // 256 workgroups  -> 1 block/CU guaranteed (LDS 53KB < 64KB)
#define NTHR 512        // threads per workgroup (8 waves)
#define KHALF 384       // K split across 2 wave-pairs

__device__ __forceinline__ float sigf(float x) { return 1.0f / (1.0f + __expf(-x)); }

__global__ void __launch_bounds__(NTHR, 2)
lstm_pers(const int* __restrict__ X, const float* __restrict__ E,
          const float* __restrict__ Ww, const float* __restrict__ Wb,
          float* __restrict__ out, float* __restrict__ ws)
{
    const int tid = threadIdx.x;
    const int bid = blockIdx.x;
    const int nb  = bid & (NGR - 1);   // n-group 0..1
    const int hb  = bid >> 1;          // h-block 0..127
    const int nl  = tid & 63;          // n within tile
    const int hl  = (tid >> 6) & (HT - 1);
    const int kq  = tid >> 8;          // k-half 0..1 (wave-uniform)
    const int ng  = nb * NT + nl;      // global n
    const int h0  = hb * HT;
    const int hg  = h0 + hl;           // global h

    // LDS: W slice [4 gates][HT rows][KD] fp32 (48KB) + reduction scratch (4KB) = 53,248B
    __shared__ float  Wl[4 * HT * KD];
    __shared__ float4 red[256];

    float* Hbuf  = ws;                             // 2 * HID * NB floats (double buffer, [k][n])
    int*   flags = (int*)(ws + 2 * HID * NB);      // NGR*HBL arrival flags
    int*   rel   = flags + NGR * HBL;              // NGR release flags (64-int spaced)

    // ---- stage W slice into LDS (once) ----
    for (int i = tid; i < (4 * HT * KD) / 4; i += NTHR) {
        int r  = i / (KD / 4);         // 0..15
        int c4 = i - r * (KD / 4);
        int g  = r >> 2, h = r & (HT - 1);
        const float4* src = (const float4*)(Ww + (size_t)(g * HID + h0 + h) * KD) + c4;
        ((float4*)Wl)[i] = *src;
    }
    // zero our slice of H[buffer 0]  (tid<256: n=tid&63, h=(tid>>6)&3)
    if (tid < NT * HT) {
        Hbuf[(h0 + ((tid >> 6) & 3)) * NB + nb * NT + (tid & 63)] = 0.0f;
    }
    // per-gate biases for gate-update threads (kq==0 threads, tid<256)
    float b0 = 0, b1 = 0, b2 = 0, b3 = 0;
    if (tid < NT * HT) {
        b0 = Wb[0 * HID + hg]; b1 = Wb[1 * HID + hg];
        b2 = Wb[2 * HID + hg]; b3 = Wb[3 * HID + hg];
    }
    float c = 0.0f;   // cell state, register-resident for whole scan
    int ep = 0;

    // ---- per-n-group barrier (128 blocks each); ws starts poisoned 0xAA (negative) ----
    auto barrier = [&](int e) {
        __syncthreads();
        if (tid == 0) {
            __threadfence();
            __hip_atomic_store(&flags[nb * HBL + hb], e, __ATOMIC_RELAXED, __HIP_MEMORY_SCOPE_AGENT);
        }
        if (hb == 0) {
            if (tid < HBL) {
                while (__hip_atomic_load(&flags[nb * HBL + tid], __ATOMIC_ACQUIRE,
                                         __HIP_MEMORY_SCOPE_AGENT) < e)
                    __builtin_amdgcn_s_sleep(1);
            }
            __syncthreads();
            if (tid == 0) {
                __threadfence();
                __hip_atomic_store(&rel[nb * 64], e, __ATOMIC_RELAXED, __HIP_MEMORY_SCOPE_AGENT);
            }
        }
        if (tid == 0) {
            while (__hip_atomic_load(&rel[nb * 64], __ATOMIC_ACQUIRE,
                                     __HIP_MEMORY_SCOPE_AGENT) < e)
                __builtin_amdgcn_s_sleep(1);
        }
        __syncthreads();
    };

    barrier(++ep);   // W staged + H0 zeroed, visible group-wide

    const int ks = kq * KHALF, ke = ks + KHALF;
    const float* wp0 = Wl + (0 * HT + hl) * KD;
    const float* wp1 = Wl + (1 * HT + hl) * KD;
    const float* wp2 = Wl + (2 * HT + hl) * KD;
    const float* wp3 = Wl + (3 * HT + hl) * KD;

    for (int t = 0; t < LSEQ; ++t) {
        const float* Hc = Hbuf + (t & 1) * (HID * NB);
        float*       Hw = Hbuf + ((t + 1) & 1) * (HID * NB);
        float a0 = 0, a1 = 0, a2 = 0, a3 = 0;
        const float* er = nullptr;
        if (ke > HID) {  // this k-range touches the embedding part (kq==1)
            int idx = X[ng * LSEQ + t];
            er = E + (size_t)idx * EMB;
        }
        #pragma unroll 2
        for (int k = ks; k < ke; k += 4) {
            float v0, v1, v2, v3;
            if (k < HID) {   // wave-uniform branch
                const float* hp = Hc + k * NB + ng;
                v0 = hp[0]; v1 = hp[NB]; v2 = hp[2 * NB]; v3 = hp[3 * NB];
            } else {
                float4 xv = *(const float4*)(er + (k - HID));
                v0 = xv.x; v1 = xv.y; v2 = xv.z; v3 = xv.w;
            }
            float4 w0 = *(const float4*)(wp0 + k);
            float4 w1 = *(const float4*)(wp1 + k);
            float4 w2 = *(const float4*)(wp2 + k);
            float4 w3 = *(const float4*)(wp3 + k);
            a0 = fmaf(v3, w0.w, fmaf(v2, w0.z, fmaf(v1, w0.y, fmaf(v0, w0.x, a0))));
            a1 = fmaf(v3, w1.w, fmaf(v2, w1.z, fmaf(v1, w1.y, fmaf(v0, w1.x, a1))));
            a2 = fmaf(v3, w2.w, fmaf(v2, w2.z, fmaf(v1, w2.y, fmaf(v0, w2.x, a2))));
            a3 = fmaf(v3, w3.w, fmaf(v2, w3.z, fmaf(v1, w3.y, fmaf(v0, w3.x, a3))));
        }
        if (kq == 1)
            red[tid & 255] = make_float4(a0, a1, a2, a3);
        __syncthreads();
        if (tid < NT * HT) {     // kq==0 threads finish the gates
            float4 r0 = red[tid];
            float F = sigf(a0 + r0.x + b0);
            float I = sigf(a1 + r0.y + b1);
            float O = sigf(a2 + r0.z + b2);
            float T = tanhf(a3 + r0.w + b3);
            c = fmaf(F, c, I * T);
            float hn = O * tanhf(c);
            Hw[hg * NB + ng] = hn;                       // coalesced: n contiguous
            if (t == LSEQ - 1) out[(size_t)ng * HID + hg] = hn;
        }
        barrier(++ep);
    }
}

extern "C" void kernel_launch(void* const* d_in, const int* in_sizes, int n_in,
                              void* d_out, int out_size, void* d_ws, size_t ws_size,
                              hipStream_t stream) {
    const int*   X   = (const int*)d_in[0];
    const float* E   = (const float*)d_in[1];
    const float* Ww  = (const float*)d_in[2];
    const float* Wb  = (const float*)d_in[3];
    float*       out = (float*)d_out;
    float*       ws  = (float*)d_ws;
    void* args[] = { (void*)&X, (void*)&E, (void*)&Ww, (void*)&Wb, (void*)&out, (void*)&ws };
    hipError_t e = hipLaunchCooperativeKernel((const void*)lstm_pers, dim3(NWG), dim3(NTHR),
                                              args, 0, stream);
    if (e != hipSuccess) {
        // Fallback: normal launch. Resource usage (53KB LDS, <=256 VGPR) guarantees
        // >=1 block/CU so a 256-block grid is co-resident on the idle 256-CU chip.
        hipLaunchKernelGGL(lstm_pers, dim3(NWG), dim3(NTHR), 0, stream,
                           X, E, Ww, Wb, out, ws);
    }
}

// Round 4
// 41507.358 us; speedup vs baseline: 2.8100x; 2.8100x over previous
//
#include <hip/hip_runtime.h>

// Problem constants
#define NB   128
#define LSEQ 2048
#define HID  512
#define EMB  256
#define KD   768
// Tiling: 256 blocks = 2 n-groups x 128 h-blocks; 512 thr = 16 nq x 4 hl x 8 kseg
#define NT    64
#define HT    4
#define NGR   2
#define HBL   128
#define NWG   256
#define NTHR  512
#define WSTR  776            // LDS W row stride: 776%32=8 -> hl rows on banks 0/8/16/24
#define HN    (HID*NB)       // one H buffer (65536 floats)
#define RING  4              // H ring depth (>= invalidate period)
#define POISON 0xAAAAAAAAu

#define AT_RLX __ATOMIC_RELAXED
#define AT_ACQ __ATOMIC_ACQUIRE
#define SCOPE  __HIP_MEMORY_SCOPE_AGENT

__device__ __forceinline__ void fma4(float4& a, const float4& v, float s) {
    a.x = fmaf(s, v.x, a.x); a.y = fmaf(s, v.y, a.y);
    a.z = fmaf(s, v.z, a.z); a.w = fmaf(s, v.w, a.w);
}
__device__ __forceinline__ void add4(float4& a, const float4& b) {
    a.x += b.x; a.y += b.y; a.z += b.z; a.w += b.w;
}
__device__ __forceinline__ float dot4(const float4& w, const float4& m) {
    return fmaf(w.x, m.x, fmaf(w.y, m.y, fmaf(w.z, m.z, w.w * m.w)));
}
__device__ __forceinline__ float sigf(float x) { return 1.0f / (1.0f + __expf(-x)); }
__device__ __forceinline__ float tanhfast(float x) { return fmaf(-2.0f, 1.0f / (1.0f + __expf(2.0f * x)), 1.0f); }

__global__ void __launch_bounds__(NTHR, 2)
lstm_pers(const int* __restrict__ X, const float* __restrict__ E,
          const float* __restrict__ Ww, const float* __restrict__ Wb,
          float* __restrict__ out, float* __restrict__ ws)
{
    const int tid  = threadIdx.x;
    const int bid  = blockIdx.x;
    const int nb   = bid & (NGR - 1);          // n-group 0..1
    const int hb   = bid >> 1;                 // h-block 0..127
    const int nq   = tid & 15;                 // n-quad within tile
    const int hl   = (tid >> 4) & 3;           // h within block
    const int kseg = tid >> 6;                 // 0..7, wave-uniform
    const int nqhl = tid & 63;
    const int n0   = nb * NT + nq * 4;         // global n (4 consecutive)
    const int hg   = hb * HT + hl;             // global h

    __shared__ float  Wl[16 * WSTR];           // 49,664 B
    __shared__ float4 red[4][2][64];           //  8,192 B  (SoA: comp/slot/lane -> b128 conflict-optimal)

    float* Hring = ws;                          // RING * HN floats (1 MB)
    int*   cnt   = (int*)(ws + RING * HN);      // [0]=init, [64]=grp0, [128]=grp1

    // ---- stage W slice into LDS (rows: g*4+h, padded stride) ----
    for (int i = tid; i < 16 * (KD / 4); i += NTHR) {
        int r = i / (KD / 4), c4 = i - r * (KD / 4);
        int g = r >> 2, h = r & 3;
        float4 v = *((const float4*)(Ww + (size_t)(g * HID + hb * HT + h) * KD) + c4);
        *(float4*)(Wl + r * WSTR + c4 * 4) = v;
    }
    // ---- zero H0 (ring slot 0), our (h,n) slice, bypass stores ----
    if (kseg == 0) {
        for (int m = 0; m < 4; ++m)
            __hip_atomic_store(&Hring[hg * NB + n0 + m], 0.0f, AT_RLX, SCOPE);
    }
    // biases for gate threads
    float bF = 0, bI = 0, bO = 0, bT = 0;
    if (kseg == 0) {
        bF = Wb[0 * HID + hg]; bI = Wb[1 * HID + hg];
        bO = Wb[2 * HID + hg]; bT = Wb[3 * HID + hg];
    }
    float c0 = 0, c1 = 0, c2 = 0, c3 = 0;       // cell state (gate threads only)

    // ---- init barrier: all 256 blocks; counters start poisoned (0xAAAAAAAA) ----
    __syncthreads();
    if (tid == 0) {
        __hip_atomic_fetch_add(&cnt[0], 1, AT_RLX, SCOPE);
        while ((unsigned)(__hip_atomic_load(&cnt[0], AT_RLX, SCOPE) - POISON) < 256u)
            __builtin_amdgcn_s_sleep(2);
    }
    __syncthreads();

    int* cg = &cnt[64 + nb * 64];               // per-n-group step counter
    const float* Wr0 = Wl + (0 * 4 + hl) * WSTR;
    const float* Wr1 = Wl + (1 * 4 + hl) * WSTR;
    const float* Wr2 = Wl + (2 * 4 + hl) * WSTR;
    const float* Wr3 = Wl + (3 * 4 + hl) * WSTR;
    const int kb = kseg * 64;                   // H-part k base
    const int jb = kseg * 32;                   // E-part j base
    const int nq_g = nb * 16 + nq;              // float4 column index in H row

    for (int t = 0; t < LSEQ; ++t) {
        // Periodic L1/L2 invalidate (agent-scope acquire load emits buffer_inv).
        // Every H line is invalidated after its previous read (4 steps ago) and
        // not refilled before its next read -> reads always miss to L3 (fresh).
        if ((t & 3) == 0)
            (void)__hip_atomic_load(&cnt[0], AT_ACQ, SCOPE);

        const float4* Hc4 = (const float4*)(Hring + (t & (RING - 1)) * HN);
        float*        Hw  = Hring + ((t + 1) & (RING - 1)) * HN;

        float4 a0 = {0,0,0,0}, a1 = {0,0,0,0}, a2 = {0,0,0,0}, a3 = {0,0,0,0};

        // ---- H part: 64 k's, cached dwordx4 loads ----
        #pragma unroll 4
        for (int kk = 0; kk < 64; kk += 4) {
            int k = kb + kk;
            float4 h0 = Hc4[(k + 0) * (NB / 4) + nq_g];
            float4 h1 = Hc4[(k + 1) * (NB / 4) + nq_g];
            float4 h2 = Hc4[(k + 2) * (NB / 4) + nq_g];
            float4 h3 = Hc4[(k + 3) * (NB / 4) + nq_g];
            float4 w0 = *(const float4*)(Wr0 + k);
            float4 w1 = *(const float4*)(Wr1 + k);
            float4 w2 = *(const float4*)(Wr2 + k);
            float4 w3 = *(const float4*)(Wr3 + k);
            fma4(a0, h0, w0.x); fma4(a0, h1, w0.y); fma4(a0, h2, w0.z); fma4(a0, h3, w0.w);
            fma4(a1, h0, w1.x); fma4(a1, h1, w1.y); fma4(a1, h2, w1.z); fma4(a1, h3, w1.w);
            fma4(a2, h0, w2.x); fma4(a2, h1, w2.y); fma4(a2, h2, w2.z); fma4(a2, h3, w2.w);
            fma4(a3, h0, w3.x); fma4(a3, h1, w3.y); fma4(a3, h2, w3.z); fma4(a3, h3, w3.w);
        }
        // ---- E part: 32 j's x 4 rows (X read directly; X is L2-resident) ----
        {
            int x0 = X[(n0 + 0) * LSEQ + t];
            int x1 = X[(n0 + 1) * LSEQ + t];
            int x2 = X[(n0 + 2) * LSEQ + t];
            int x3 = X[(n0 + 3) * LSEQ + t];
            const float* e0 = E + (size_t)x0 * EMB;
            const float* e1 = E + (size_t)x1 * EMB;
            const float* e2 = E + (size_t)x2 * EMB;
            const float* e3 = E + (size_t)x3 * EMB;
            #pragma unroll 4
            for (int jj = 0; jj < 32; jj += 4) {
                int j = jb + jj;
                float4 m0 = *(const float4*)(e0 + j);
                float4 m1 = *(const float4*)(e1 + j);
                float4 m2 = *(const float4*)(e2 + j);
                float4 m3 = *(const float4*)(e3 + j);
                float4 w0 = *(const float4*)(Wr0 + HID + j);
                float4 w1 = *(const float4*)(Wr1 + HID + j);
                float4 w2 = *(const float4*)(Wr2 + HID + j);
                float4 w3 = *(const float4*)(Wr3 + HID + j);
                a0.x += dot4(w0, m0); a0.y += dot4(w0, m1); a0.z += dot4(w0, m2); a0.w += dot4(w0, m3);
                a1.x += dot4(w1, m0); a1.y += dot4(w1, m1); a1.z += dot4(w1, m2); a1.w += dot4(w1, m3);
                a2.x += dot4(w2, m0); a2.y += dot4(w2, m1); a2.z += dot4(w2, m2); a2.w += dot4(w2, m3);
                a3.x += dot4(w3, m0); a3.y += dot4(w3, m1); a3.z += dot4(w3, m2); a3.w += dot4(w3, m3);
            }
        }

        // ---- cross-kseg reduction (8 -> 1) ----
        #define ST(slot) { red[0][slot][nqhl]=a0; red[1][slot][nqhl]=a1; red[2][slot][nqhl]=a2; red[3][slot][nqhl]=a3; }
        #define LD(slot) { add4(a0, red[0][slot][nqhl]); add4(a1, red[1][slot][nqhl]); \
                           add4(a2, red[2][slot][nqhl]); add4(a3, red[3][slot][nqhl]); }
        if (kseg == 4 || kseg == 5) ST(kseg - 4);
        __syncthreads();
        if (kseg == 0 || kseg == 1) LD(kseg);
        __syncthreads();
        if (kseg == 6 || kseg == 7) ST(kseg - 6);
        __syncthreads();
        if (kseg == 2 || kseg == 3) LD(kseg - 2);
        __syncthreads();
        if (kseg == 2 || kseg == 3) ST(kseg - 2);
        __syncthreads();
        if (kseg == 0 || kseg == 1) LD(kseg);
        __syncthreads();
        if (kseg == 1) ST(0);
        __syncthreads();
        if (kseg == 0) LD(0);

        // ---- gates + state update + H publish (wave 0 only) ----
        if (kseg == 0) {
            float F, I, O, T, hn;
            F = sigf(a0.x + bF); I = sigf(a1.x + bI); O = sigf(a2.x + bO); T = tanhfast(a3.x + bT);
            c0 = fmaf(F, c0, I * T); hn = O * tanhfast(c0);
            __hip_atomic_store(&Hw[hg * NB + n0 + 0], hn, AT_RLX, SCOPE);
            if (t == LSEQ - 1) __hip_atomic_store(&out[(size_t)(n0 + 0) * HID + hg], hn, AT_RLX, SCOPE);
            F = sigf(a0.y + bF); I = sigf(a1.y + bI); O = sigf(a2.y + bO); T = tanhfast(a3.y + bT);
            c1 = fmaf(F, c1, I * T); hn = O * tanhfast(c1);
            __hip_atomic_store(&Hw[hg * NB + n0 + 1], hn, AT_RLX, SCOPE);
            if (t == LSEQ - 1) __hip_atomic_store(&out[(size_t)(n0 + 1) * HID + hg], hn, AT_RLX, SCOPE);
            F = sigf(a0.z + bF); I = sigf(a1.z + bI); O = sigf(a2.z + bO); T = tanhfast(a3.z + bT);
            c2 = fmaf(F, c2, I * T); hn = O * tanhfast(c2);
            __hip_atomic_store(&Hw[hg * NB + n0 + 2], hn, AT_RLX, SCOPE);
            if (t == LSEQ - 1) __hip_atomic_store(&out[(size_t)(n0 + 2) * HID + hg], hn, AT_RLX, SCOPE);
            F = sigf(a0.w + bF); I = sigf(a1.w + bI); O = sigf(a2.w + bO); T = tanhfast(a3.w + bT);
            c3 = fmaf(F, c3, I * T); hn = O * tanhfast(c3);
            __hip_atomic_store(&Hw[hg * NB + n0 + 3], hn, AT_RLX, SCOPE);
            if (t == LSEQ - 1) __hip_atomic_store(&out[(size_t)(n0 + 3) * HID + hg], hn, AT_RLX, SCOPE);
        }

        // ---- per-n-group barrier: relaxed counter, no invalidates in the poll ----
        __syncthreads();                        // drains vmem (H stores complete at L3)
        if (tid == 0) {
            __hip_atomic_fetch_add(cg, 1, AT_RLX, SCOPE);
            unsigned need = 128u * (unsigned)(t + 1);
            while ((unsigned)(__hip_atomic_load(cg, AT_RLX, SCOPE) - POISON) < need)
                __builtin_amdgcn_s_sleep(2);
        }
        __syncthreads();
    }
}

extern "C" void kernel_launch(void* const* d_in, const int* in_sizes, int n_in,
                              void* d_out, int out_size, void* d_ws, size_t ws_size,
                              hipStream_t stream) {
    const int*   X   = (const int*)d_in[0];
    const float* E   = (const float*)d_in[1];
    const float* Ww  = (const float*)d_in[2];
    const float* Wb  = (const float*)d_in[3];
    float*       out = (float*)d_out;
    float*       ws  = (float*)d_ws;
    void* args[] = { (void*)&X, (void*)&E, (void*)&Ww, (void*)&Wb, (void*)&out, (void*)&ws };
    hipError_t e = hipLaunchCooperativeKernel((const void*)lstm_pers, dim3(NWG), dim3(NTHR),
                                              args, 0, stream);
    if (e != hipSuccess) {
        // 256 blocks, 57.9KB LDS, <=256 VGPR -> 1 block/CU guaranteed co-resident.
        hipLaunchKernelGGL(lstm_pers, dim3(NWG), dim3(NTHR), 0, stream,
                           X, E, Ww, Wb, out, ws);
    }
}

// Round 5
// 34902.011 us; speedup vs baseline: 3.3418x; 1.1893x over previous
//
#include <hip/hip_runtime.h>

// Problem constants
#define NB   128
#define LSEQ 2048
#define HID  512
#define EMB  256
#define KD   768
// Tiling: 256 blocks = 2 n-groups x 128 h-blocks; 512 thr = 16 nq x 4 hl x 8 kseg
#define NT    64
#define HT    4
#define NGR   2
#define HBL   128
#define NWG   256
#define NTHR  512
#define WSTR  776            // LDS W row stride: 776%32=8 -> hl rows on banks 0/8/16/24
#define HN    (HID*NB)       // one H buffer (65536 floats)
#define RING  4              // H ring depth

#define AT_RLX __ATOMIC_RELAXED
#define AT_ACQ __ATOMIC_ACQUIRE
#define AT_REL __ATOMIC_RELEASE
#define SCOPE  __HIP_MEMORY_SCOPE_AGENT

__device__ __forceinline__ void fma4(float4& a, const float4& v, float s) {
    a.x = fmaf(s, v.x, a.x); a.y = fmaf(s, v.y, a.y);
    a.z = fmaf(s, v.z, a.z); a.w = fmaf(s, v.w, a.w);
}
__device__ __forceinline__ void add4(float4& a, const float4& b) {
    a.x += b.x; a.y += b.y; a.z += b.z; a.w += b.w;
}
__device__ __forceinline__ float dot4(const float4& w, const float4& m) {
    return fmaf(w.x, m.x, fmaf(w.y, m.y, fmaf(w.z, m.z, w.w * m.w)));
}
__device__ __forceinline__ float sigf(float x) { return 1.0f / (1.0f + __expf(-x)); }
__device__ __forceinline__ float tanhfast(float x) { return fmaf(-2.0f, 1.0f / (1.0f + __expf(2.0f * x)), 1.0f); }

__global__ void __launch_bounds__(NTHR, 2)
lstm_pers(const int* __restrict__ X, const float* __restrict__ E,
          const float* __restrict__ Ww, const float* __restrict__ Wb,
          float* __restrict__ out, float* __restrict__ ws)
{
    const int tid  = threadIdx.x;
    const int bid  = blockIdx.x;
    const int nb   = bid & (NGR - 1);          // n-group 0..1
    const int hb   = bid >> 1;                 // h-block 0..127
    const int nq   = tid & 15;                 // n-quad within tile
    const int hl   = (tid >> 4) & 3;           // h within block
    const int kseg = tid >> 6;                 // 0..7, wave-uniform
    const int nqhl = tid & 63;
    const int n0   = nb * NT + nq * 4;         // global n (4 consecutive)
    const int hg   = hb * HT + hl;             // global h

    __shared__ float  Wl[16 * WSTR];           // 49,664 B
    __shared__ float4 red[4][2][64];           //  8,192 B  (SoA, b128 conflict-free)

    float* Hring = ws;                          // RING * HN floats (1 MB)
    int*   flags = (int*)(ws + RING * HN);      // [nb][HBL] per-block epoch flags

    // ---- stage W slice into LDS ----
    for (int i = tid; i < 16 * (KD / 4); i += NTHR) {
        int r = i / (KD / 4), c4 = i - r * (KD / 4);
        int g = r >> 2, h = r & 3;
        float4 v = *((const float4*)(Ww + (size_t)(g * HID + hb * HT + h) * KD) + c4);
        *(float4*)(Wl + r * WSTR + c4 * 4) = v;
    }
    // ---- zero H(0) slice (ring slot 0), bypass stores (wave 0 only) ----
    if (kseg == 0) {
        for (int m = 0; m < 4; ++m)
            __hip_atomic_store(&Hring[hg * NB + n0 + m], 0.0f, AT_RLX, SCOPE);
    }
    float bF = 0, bI = 0, bO = 0, bT = 0;
    if (kseg == 0) {
        bF = Wb[0 * HID + hg]; bI = Wb[1 * HID + hg];
        bO = Wb[2 * HID + hg]; bT = Wb[3 * HID + hg];
    }
    float c0 = 0, c1 = 0, c2 = 0, c3 = 0;       // cell state (wave-0 threads)

    // publish "H(0) ready": release store orders wave-0's zero-stores before it.
    // flags start poisoned (0xAAAAAAAA = negative int) -> signed compare works.
    if (tid == 0) __hip_atomic_store(&flags[nb * HBL + hb], 0, AT_REL, SCOPE);

    const float* Wr0 = Wl + (0 * 4 + hl) * WSTR;
    const float* Wr1 = Wl + (1 * 4 + hl) * WSTR;
    const float* Wr2 = Wl + (2 * 4 + hl) * WSTR;
    const float* Wr3 = Wl + (3 * 4 + hl) * WSTR;
    const int kb = kseg * 64;                   // H-part k base
    const int jb = kseg * 32;                   // E-part j base
    const int nq_g = nb * 16 + nq;              // float4 column index in H row

    for (int t = 0; t < LSEQ; ++t) {
        float4 a0 = {0,0,0,0}, a1 = {0,0,0,0}, a2 = {0,0,0,0}, a3 = {0,0,0,0};

        // ---- E-part FIRST (no H dependency; hides producer->flag latency) ----
        {
            int x0 = X[(n0 + 0) * LSEQ + t];
            int x1 = X[(n0 + 1) * LSEQ + t];
            int x2 = X[(n0 + 2) * LSEQ + t];
            int x3 = X[(n0 + 3) * LSEQ + t];
            const float* e0 = E + (size_t)x0 * EMB;
            const float* e1 = E + (size_t)x1 * EMB;
            const float* e2 = E + (size_t)x2 * EMB;
            const float* e3 = E + (size_t)x3 * EMB;
            #pragma unroll 4
            for (int jj = 0; jj < 32; jj += 4) {
                int j = jb + jj;
                float4 m0 = *(const float4*)(e0 + j);
                float4 m1 = *(const float4*)(e1 + j);
                float4 m2 = *(const float4*)(e2 + j);
                float4 m3 = *(const float4*)(e3 + j);
                float4 w0 = *(const float4*)(Wr0 + HID + j);
                float4 w1 = *(const float4*)(Wr1 + HID + j);
                float4 w2 = *(const float4*)(Wr2 + HID + j);
                float4 w3 = *(const float4*)(Wr3 + HID + j);
                a0.x += dot4(w0, m0); a0.y += dot4(w0, m1); a0.z += dot4(w0, m2); a0.w += dot4(w0, m3);
                a1.x += dot4(w1, m0); a1.y += dot4(w1, m1); a1.z += dot4(w1, m2); a1.w += dot4(w1, m3);
                a2.x += dot4(w2, m0); a2.y += dot4(w2, m1); a2.z += dot4(w2, m2); a2.w += dot4(w2, m3);
                a3.x += dot4(w3, m0); a3.y += dot4(w3, m1); a3.z += dot4(w3, m2); a3.w += dot4(w3, m3);
            }
        }

        // ---- wave 0: poll the 128 per-block flags of our n-group (>= t) ----
        if (tid < 64) {
            const int* fp = flags + nb * HBL;
            while (true) {
                int f0 = __hip_atomic_load(&fp[2 * tid],     AT_RLX, SCOPE);
                int f1 = __hip_atomic_load(&fp[2 * tid + 1], AT_RLX, SCOPE);
                if (__all((f0 >= t) & (f1 >= t))) break;
                __builtin_amdgcn_s_sleep(1);
            }
            // Every 4 steps: acquire (buffer_inv) so cached H reads can never be
            // staler than RING. Slot-t lines were last cached 4 steps ago; exactly
            // one invalidate lands in between -> the read below misses to LLC,
            // which holds the post-release data (flag seen => h-stores at LLC).
            if ((t & 3) == 0)
                (void)__hip_atomic_load(&fp[2 * tid], AT_ACQ, SCOPE);
        }
        __syncthreads();   // also orders the invalidate before all waves' H loads

        const float4* Hc4 = (const float4*)(Hring + (t & (RING - 1)) * HN);
        float*        Hw  = Hring + ((t + 1) & (RING - 1)) * HN;

        // ---- H-part: 64 k's, cached dwordx4 loads ----
        #pragma unroll 4
        for (int kk = 0; kk < 64; kk += 4) {
            int k = kb + kk;
            float4 h0 = Hc4[(k + 0) * (NB / 4) + nq_g];
            float4 h1 = Hc4[(k + 1) * (NB / 4) + nq_g];
            float4 h2 = Hc4[(k + 2) * (NB / 4) + nq_g];
            float4 h3 = Hc4[(k + 3) * (NB / 4) + nq_g];
            float4 w0 = *(const float4*)(Wr0 + k);
            float4 w1 = *(const float4*)(Wr1 + k);
            float4 w2 = *(const float4*)(Wr2 + k);
            float4 w3 = *(const float4*)(Wr3 + k);
            fma4(a0, h0, w0.x); fma4(a0, h1, w0.y); fma4(a0, h2, w0.z); fma4(a0, h3, w0.w);
            fma4(a1, h0, w1.x); fma4(a1, h1, w1.y); fma4(a1, h2, w1.z); fma4(a1, h3, w1.w);
            fma4(a2, h0, w2.x); fma4(a2, h1, w2.y); fma4(a2, h2, w2.z); fma4(a2, h3, w2.w);
            fma4(a3, h0, w3.x); fma4(a3, h1, w3.y); fma4(a3, h2, w3.z); fma4(a3, h3, w3.w);
        }

        // ---- cross-kseg reduction (8 -> 1) ----
        #define ST(slot) { red[0][slot][nqhl]=a0; red[1][slot][nqhl]=a1; red[2][slot][nqhl]=a2; red[3][slot][nqhl]=a3; }
        #define LD(slot) { add4(a0, red[0][slot][nqhl]); add4(a1, red[1][slot][nqhl]); \
                           add4(a2, red[2][slot][nqhl]); add4(a3, red[3][slot][nqhl]); }
        if (kseg == 4 || kseg == 5) ST(kseg - 4);
        __syncthreads();
        if (kseg == 0 || kseg == 1) LD(kseg);
        __syncthreads();
        if (kseg == 6 || kseg == 7) ST(kseg - 6);
        __syncthreads();
        if (kseg == 2 || kseg == 3) LD(kseg - 2);
        __syncthreads();
        if (kseg == 2 || kseg == 3) ST(kseg - 2);
        __syncthreads();
        if (kseg == 0 || kseg == 1) LD(kseg);
        __syncthreads();
        if (kseg == 1) ST(0);
        __syncthreads();
        if (kseg == 0) LD(0);

        // ---- gates + state update + H publish (wave 0 only) ----
        if (kseg == 0) {
            float F, I, O, T, hn;
            F = sigf(a0.x + bF); I = sigf(a1.x + bI); O = sigf(a2.x + bO); T = tanhfast(a3.x + bT);
            c0 = fmaf(F, c0, I * T); hn = O * tanhfast(c0);
            __hip_atomic_store(&Hw[hg * NB + n0 + 0], hn, AT_RLX, SCOPE);
            if (t == LSEQ - 1) __hip_atomic_store(&out[(size_t)(n0 + 0) * HID + hg], hn, AT_RLX, SCOPE);
            F = sigf(a0.y + bF); I = sigf(a1.y + bI); O = sigf(a2.y + bO); T = tanhfast(a3.y + bT);
            c1 = fmaf(F, c1, I * T); hn = O * tanhfast(c1);
            __hip_atomic_store(&Hw[hg * NB + n0 + 1], hn, AT_RLX, SCOPE);
            if (t == LSEQ - 1) __hip_atomic_store(&out[(size_t)(n0 + 1) * HID + hg], hn, AT_RLX, SCOPE);
            F = sigf(a0.z + bF); I = sigf(a1.z + bI); O = sigf(a2.z + bO); T = tanhfast(a3.z + bT);
            c2 = fmaf(F, c2, I * T); hn = O * tanhfast(c2);
            __hip_atomic_store(&Hw[hg * NB + n0 + 2], hn, AT_RLX, SCOPE);
            if (t == LSEQ - 1) __hip_atomic_store(&out[(size_t)(n0 + 2) * HID + hg], hn, AT_RLX, SCOPE);
            F = sigf(a0.w + bF); I = sigf(a1.w + bI); O = sigf(a2.w + bO); T = tanhfast(a3.w + bT);
            c3 = fmaf(F, c3, I * T); hn = O * tanhfast(c3);
            __hip_atomic_store(&Hw[hg * NB + n0 + 3], hn, AT_RLX, SCOPE);
            if (t == LSEQ - 1) __hip_atomic_store(&out[(size_t)(n0 + 3) * HID + hg], hn, AT_RLX, SCOPE);
        }
        // Release: orders wave-0's h-stores (same wave) before the flag becomes
        // visible. No block-wide barrier, no atomic RMW -> no serialization.
        if (tid == 0)
            __hip_atomic_store(&flags[nb * HBL + hb], t + 1, AT_REL, SCOPE);
        // red-slot reuse across iterations is protected by the top-of-loop
        // __syncthreads (no wave can ST before wave 0 passed its LD(0)).
    }
}

extern "C" void kernel_launch(void* const* d_in, const int* in_sizes, int n_in,
                              void* d_out, int out_size, void* d_ws, size_t ws_size,
                              hipStream_t stream) {
    const int*   X   = (const int*)d_in[0];
    const float* E   = (const float*)d_in[1];
    const float* Ww  = (const float*)d_in[2];
    const float* Wb  = (const float*)d_in[3];
    float*       out = (float*)d_out;
    float*       ws  = (float*)d_ws;
    void* args[] = { (void*)&X, (void*)&E, (void*)&Ww, (void*)&Wb, (void*)&out, (void*)&ws };
    hipError_t e = hipLaunchCooperativeKernel((const void*)lstm_pers, dim3(NWG), dim3(NTHR),
                                              args, 0, stream);
    if (e != hipSuccess) {
        // 256 blocks, 57.9KB LDS -> 1 block/CU, all co-resident on idle 256-CU chip.
        hipLaunchKernelGGL(lstm_pers, dim3(NWG), dim3(NTHR), 0, stream,
                           X, E, Ww, Wb, out, ws);
    }
}